// Round 7
// baseline (219.535 us; speedup 1.0000x reference)
//
#include <hip/hip_runtime.h>
#include <cstdint>
#include <cstddef>

typedef _Float16 half8 __attribute__((ext_vector_type(8)));
typedef __fp16 fp16x2 __attribute__((ext_vector_type(2)));
typedef float floatx16 __attribute__((ext_vector_type(16)));

// LDS frag arena, chunk = 1024 B = 64 lanes x 16 B; lane l of chunk (tile,ks)
// holds A[row = tile*32 + (l&31)][k = ks*16 + (l>>5)*8 + i], i = 0..7.
//   W0c: chunks (mt*4+ks), mt 0..3, ks 0..3 @ 0      k<48: W0[(16+k)*128+j];
//        k==48: cbias(c,j) = b0[j] + emb_c . W0[0:16,j]; else 0
//   W1 : chunks (mt*9+ks), mt 0..3, ks 0..8 @ 16384  k<128: W1[k*128+j]; k==128: b1[j]; else 0
//   W2 : chunks ks 0..8            @ 53248           row o<3: k<128: W2[k*3+o]; k==128: b2[o]; else 0
// total 61 chunks = 62464 B

union U4 { unsigned u[4]; half8 h; };

__device__ __forceinline__ unsigned pkr(float a, float b) {
    union { fp16x2 h; unsigned u; } x;
    x.h = __builtin_amdgcn_cvt_pkrtz(a, b);
    return x.u;
}

// acc tile (C-layout) -> two B-frag half8 chunks via relu+pack+lane^32 exchange.
__device__ __forceinline__ void transition(const floatx16& a, int hl,
                                           half8& lo, half8& hi) {
    unsigned p0 = pkr(fmaxf(a[0],  0.f), fmaxf(a[1],  0.f));
    unsigned p1 = pkr(fmaxf(a[2],  0.f), fmaxf(a[3],  0.f));
    unsigned p2 = pkr(fmaxf(a[4],  0.f), fmaxf(a[5],  0.f));
    unsigned p3 = pkr(fmaxf(a[6],  0.f), fmaxf(a[7],  0.f));
    unsigned p4 = pkr(fmaxf(a[8],  0.f), fmaxf(a[9],  0.f));
    unsigned p5 = pkr(fmaxf(a[10], 0.f), fmaxf(a[11], 0.f));
    unsigned p6 = pkr(fmaxf(a[12], 0.f), fmaxf(a[13], 0.f));
    unsigned p7 = pkr(fmaxf(a[14], 0.f), fmaxf(a[15], 0.f));
    unsigned r0 = __shfl_xor(hl ? p0 : p2, 32);
    unsigned r1 = __shfl_xor(hl ? p1 : p3, 32);
    unsigned r2 = __shfl_xor(hl ? p4 : p6, 32);
    unsigned r3 = __shfl_xor(hl ? p5 : p7, 32);
    U4 L, H;
    L.u[0] = hl ? r0 : p0;
    L.u[1] = hl ? r1 : p1;
    L.u[2] = hl ? p2 : r0;
    L.u[3] = hl ? p3 : r1;
    H.u[0] = hl ? r2 : p4;
    H.u[1] = hl ? r3 : p5;
    H.u[2] = hl ? p6 : r2;
    H.u[3] = hl ? p7 : r3;
    lo = L.h; hi = H.h;
}

#define MFMA(a, b, c) __builtin_amdgcn_mfma_f32_32x32x16_f16((a), (b), (c), 0, 0, 0)

__global__ __launch_bounds__(512, 4) void vdc_mlp_kernel(
    const float* __restrict__ feats,      // [N,32]
    const float* __restrict__ dirs,       // [C,N,3]
    const float* __restrict__ emb_tab,    // [1000,16]
    const float* __restrict__ W0,         // [64,128]
    const float* __restrict__ b0,         // [128]
    const float* __restrict__ W1,         // [128,128]
    const float* __restrict__ b1,         // [128]
    const float* __restrict__ W2,         // [128,3]
    const float* __restrict__ b2,         // [3]
    const int* __restrict__ embed_ids,    // [C]
    const int* __restrict__ sh_deg_p,     // [1]
    float* __restrict__ out,              // [C,N,3]
    int N)
{
    __shared__ uint4 arena[3904];         // 62464 B
    char* lds = (char*)arena;

    const int tid   = threadIdx.x;
    const int c     = blockIdx.y;
    const int w     = tid >> 6;           // 0..7
    const int lane  = tid & 63;
    const int ln    = lane & 31;
    const int hl    = lane >> 5;
    const int base  = blockIdx.x * 256 + w * 32;   // this wave's 32 elements

    // ---- phase 0a: zero the arena (bias/pad regions need it) ----
    #pragma unroll
    for (int q = 0; q < 8; ++q) {
        int idx = q * 512 + tid;
        if (idx < 3904) arena[idx] = uint4{0, 0, 0, 0};
    }
    __syncthreads();

    // ---- phase 0b: scatter-fill frag chunks from original weights ----
    // W1 body: 4096 float4, 8 per thread
    #pragma unroll
    for (int q = 0; q < 8; ++q) {
        int fidx = q * 512 + tid;
        int k   = fidx >> 5;
        int j4  = (fidx & 31) * 4;
        float4 v = *(const float4*)(W1 + k * 128 + j4);
        int ks = k >> 4;
        int lv = 32 * ((k >> 3) & 1);
        int by = (k & 7) * 2;
        float vv[4] = {v.x, v.y, v.z, v.w};
        #pragma unroll
        for (int d = 0; d < 4; ++d) {
            int j = j4 + d;
            char* p = lds + 16384 + ((j >> 5) * 9 + ks) * 1024 + ((j & 31) + lv) * 16 + by;
            *(_Float16*)p = (_Float16)vv[d];
        }
    }
    // W0 rows 16..63: 1536 float4, 3 per thread
    #pragma unroll
    for (int q = 0; q < 3; ++q) {
        int fidx = q * 512 + tid;
        int kk  = fidx >> 5;
        int j4  = (fidx & 31) * 4;
        float4 v = *(const float4*)(W0 + (16 + kk) * 128 + j4);
        int ks = kk >> 4;
        int lv = 32 * ((kk >> 3) & 1);
        int by = (kk & 7) * 2;
        float vv[4] = {v.x, v.y, v.z, v.w};
        #pragma unroll
        for (int d = 0; d < 4; ++d) {
            int j = j4 + d;
            char* p = lds + ((j >> 5) * 4 + ks) * 1024 + ((j & 31) + lv) * 16 + by;
            *(_Float16*)p = (_Float16)vv[d];
        }
    }
    // cbias (k'==48 -> chunk mt*4+3, lane j&31, byte 0) + b1 (W1 ks=8 chunk)
    if (tid < 128) {
        int j = tid;
        int id = embed_ids[c];
        float a = b0[j];
        #pragma unroll
        for (int e = 0; e < 16; ++e)
            a += emb_tab[(size_t)id * 16 + e] * W0[e * 128 + j];
        *(_Float16*)(lds + ((j >> 5) * 4 + 3) * 1024 + (j & 31) * 16) = (_Float16)a;
        *(_Float16*)(lds + 16384 + ((j >> 5) * 9 + 8) * 1024 + (j & 31) * 16) = (_Float16)b1[j];
    } else if (tid < 512 && tid >= 128 && tid < 128 + 384) {
        // W2: 384 elements
        int t = tid - 128;
        int k = t / 3, o = t - 3 * k;
        float v = W2[k * 3 + o];
        char* p = lds + 53248 + (k >> 4) * 1024 + (o + 32 * ((k >> 3) & 1)) * 16 + (k & 7) * 2;
        *(_Float16*)p = (_Float16)v;
    }
    if (tid < 3)
        *(_Float16*)(lds + 53248 + 8 * 1024 + tid * 16) = (_Float16)b2[tid];

    // ---- phase 1: build layer0 B-frags (registers only; overlaps staging) ----
    half8 bx0, bx1, bx2, bbias;
    {
        U4 ub;
        ub.u[0] = hl ? 0u : 0x00003C00u;   // f16 1.0 at k-offset 0, hl=0 only
        ub.u[1] = 0u; ub.u[2] = 0u; ub.u[3] = 0u;
        bbias = ub.h;
    }
    {
        int n = base + ln; if (n >= N) n = N - 1;
        const float* fp = feats + (size_t)n * 32 + hl * 8;
        float4 f0 = *(const float4*)(fp);
        float4 f1 = *(const float4*)(fp + 4);
        float4 f2 = *(const float4*)(fp + 16);
        float4 f3 = *(const float4*)(fp + 20);
        U4 u0, u1;
        u0.u[0] = pkr(f0.x, f0.y); u0.u[1] = pkr(f0.z, f0.w);
        u0.u[2] = pkr(f1.x, f1.y); u0.u[3] = pkr(f1.z, f1.w);
        u1.u[0] = pkr(f2.x, f2.y); u1.u[1] = pkr(f2.z, f2.w);
        u1.u[2] = pkr(f3.x, f3.y); u1.u[3] = pkr(f3.z, f3.w);
        bx0 = u0.h; bx1 = u1.h;

        const float* dp = dirs + ((size_t)c * N + n) * 3;
        float dx = dp[0], dy = dp[1], dz = dp[2];
        float nrm = sqrtf(dx * dx + dy * dy + dz * dz);
        float inv = 1.0f / fmaxf(nrm, 1e-12f);
        float x = dx * inv, y = dy * inv, z = dz * inv;

        float z2     = z * z;
        float fTmp0B = -1.092548430592079f * z;
        float fC1    = x * x - y * y;
        float fS1    = 2.0f * x * y;
        float fTmp0C = -2.285228997322329f * z2 + 0.4570457994644658f;
        float fTmp1B = 1.445305721320277f * z;
        float fC2    = x * fC1 - y * fS1;
        float fS2    = x * fS1 + y * fC1;

        float sh[16];
        sh[0]  = 0.2820947917738781f;
        sh[1]  = -0.48860251190292f * y;
        sh[2]  = 0.48860251190292f * z;
        sh[3]  = -0.48860251190292f * x;
        sh[4]  = 0.5462742152960395f * fS1;
        sh[5]  = fTmp0B * y;
        sh[6]  = 0.9461746957575601f * z2 - 0.3153915652525201f;
        sh[7]  = fTmp0B * x;
        sh[8]  = 0.5462742152960395f * fC1;
        sh[9]  = -0.5900435899266435f * fS2;
        sh[10] = fTmp1B * fS1;
        sh[11] = fTmp0C * y;
        sh[12] = z * (1.865881662950577f * z2 - 1.119528997770346f);
        sh[13] = fTmp0C * x;
        sh[14] = fTmp1B * fC1;
        sh[15] = -0.5900435899266435f * fC2;

        int deg = sh_deg_p[0];
        int nbu = (deg + 1) * (deg + 1);
        #pragma unroll
        for (int i = 0; i < 16; ++i) if (i >= nbu) sh[i] = 0.0f;

        float s[8];
        #pragma unroll
        for (int i = 0; i < 8; ++i) s[i] = hl ? sh[8 + i] : sh[i];
        U4 u2;
        u2.u[0] = pkr(s[0], s[1]); u2.u[1] = pkr(s[2], s[3]);
        u2.u[2] = pkr(s[4], s[5]); u2.u[3] = pkr(s[6], s[7]);
        bx2 = u2.h;
    }

    __syncthreads();

    const char* fr = lds + lane * 16;     // per-lane frag base; chunk offsets imm

    // ---- layer 0 + transition -> hx ----
    half8 hx[8];
    #pragma unroll
    for (int mt = 0; mt < 4; ++mt) {
        half8 a0 = *(const half8*)(fr + (mt * 4 + 0) * 1024);
        half8 a1 = *(const half8*)(fr + (mt * 4 + 1) * 1024);
        half8 a2 = *(const half8*)(fr + (mt * 4 + 2) * 1024);
        half8 a3 = *(const half8*)(fr + (mt * 4 + 3) * 1024);
        floatx16 acc;
        #pragma unroll
        for (int r = 0; r < 16; ++r) acc[r] = 0.0f;
        acc = MFMA(a0, bx0, acc);
        acc = MFMA(a1, bx1, acc);
        acc = MFMA(a2, bx2, acc);
        acc = MFMA(a3, bbias, acc);
        transition(acc, hl, hx[2 * mt], hx[2 * mt + 1]);
    }

    // ---- layer 1 + transition -> gx ----
    half8 gx[8];
    #pragma unroll
    for (int mt = 0; mt < 4; ++mt) {
        const char* ap = fr + 16384 + mt * 9 * 1024;
        floatx16 acc;
        #pragma unroll
        for (int r = 0; r < 16; ++r) acc[r] = 0.0f;
        #pragma unroll
        for (int ks = 0; ks < 8; ++ks) {
            half8 a = *(const half8*)(ap + ks * 1024);
            acc = MFMA(a, hx[ks], acc);
        }
        half8 ab = *(const half8*)(ap + 8 * 1024);
        acc = MFMA(ab, bbias, acc);
        transition(acc, hl, gx[2 * mt], gx[2 * mt + 1]);
    }

    // ---- layer 2: rows >=3 garbage, never stored ----
    {
        floatx16 acc;
        #pragma unroll
        for (int r = 0; r < 16; ++r) acc[r] = 0.0f;
        const char* ap = fr + 53248;
        #pragma unroll
        for (int ks = 0; ks < 8; ++ks) {
            half8 a = *(const half8*)(ap + ks * 1024);
            acc = MFMA(a, gx[ks], acc);
        }
        half8 ab = *(const half8*)(ap + 8 * 1024);
        acc = MFMA(ab, bbias, acc);

        if (hl == 0) {
            int nn = base + ln;
            if (nn < N) {
                float* op = out + ((size_t)c * N + nn) * 3;
                op[0] = acc[0];
                op[1] = acc[1];
                op[2] = acc[2];
            }
        }
    }
}

extern "C" void kernel_launch(void* const* d_in, const int* in_sizes, int n_in,
                              void* d_out, int out_size, void* d_ws, size_t ws_size,
                              hipStream_t stream) {
    const float* feats   = (const float*)d_in[0];
    const float* dirs    = (const float*)d_in[1];
    const float* emb_tab = (const float*)d_in[2];
    const float* W0      = (const float*)d_in[3];
    const float* b0      = (const float*)d_in[4];
    const float* W1      = (const float*)d_in[5];
    const float* b1      = (const float*)d_in[6];
    const float* W2      = (const float*)d_in[7];
    const float* b2      = (const float*)d_in[8];
    const int*   eids    = (const int*)d_in[9];
    const int*   shd     = (const int*)d_in[10];
    float* outp          = (float*)d_out;

    int N = in_sizes[0] / 32;    // features [N,32]
    int C = in_sizes[9];         // embed_ids [C]

    dim3 grid((N + 255) / 256, C);
    vdc_mlp_kernel<<<grid, 512, 0, stream>>>(
        feats, dirs, emb_tab, W0, b0, W1, b1, W2, b2, eids, shd, outp, N);
}

// Round 8
// 165.040 us; speedup vs baseline: 1.3302x; 1.3302x over previous
//
#include <hip/hip_runtime.h>
#include <cstdint>
#include <cstddef>

typedef _Float16 half8 __attribute__((ext_vector_type(8)));
typedef __fp16 fp16x2 __attribute__((ext_vector_type(2)));
typedef float floatx16 __attribute__((ext_vector_type(16)));

// ws: frag-linear weight blobs. chunk = 1024 B = 64 lanes x 8 f16, lane l holds
// A[row = tile*32 + (l&31)][k = kchunk*16 + (l>>5)*8 + i], i=0..7.
//   W0c [C][16 chunks]  @ f16 0       (mt 0..3) x (ks 0..3); k<48: W0[(16+k)*128+j],
//                                     k==48: cbias(c,j)=b0[j]+emb_c.W0[0:16,j], else 0
//   W1  [36 chunks]     @ C*8192      (mt 0..3) x (ks 0..8); k<128: W1[k*128+j], k==128: b1[j], else 0
//   W2  [9 chunks]      @ C*8192+18432  (ks 0..8); o=(l&31): o<3 ? (k<128? W2[k*3+o] : k==128? b2[o] : 0) : 0

__global__ void vdc_prep_kernel(const float* __restrict__ W0,
                                const float* __restrict__ W1,
                                const float* __restrict__ W2,
                                const float* __restrict__ b0,
                                const float* __restrict__ b1,
                                const float* __restrict__ b2,
                                const float* __restrict__ emb_tab,
                                const int* __restrict__ embed_ids,
                                int C,
                                _Float16* __restrict__ ws) {
    int i = blockIdx.x * 256 + threadIdx.x;
    int w0end = C * 8192;
    int w1end = w0end + 18432;
    int w2end = w1end + 4608;
    float v = 0.0f;
    if (i < w0end) {
        int c = i >> 13, r = i & 8191;
        int ci = r >> 9, l = (r >> 3) & 63, ii = r & 7;
        int mt = ci >> 2, ks = ci & 3;
        int j  = mt * 32 + (l & 31);
        int kk = ks * 16 + (l >> 5) * 8 + ii;
        if (kk < 48) v = W0[(16 + kk) * 128 + j];
        else if (kk == 48) {
            int id = embed_ids[c];
            v = b0[j];
            #pragma unroll
            for (int e = 0; e < 16; ++e)
                v += emb_tab[(size_t)id * 16 + e] * W0[e * 128 + j];
        }
        ws[i] = (_Float16)v;
    } else if (i < w1end) {
        int r = i - w0end;
        int ci = r >> 9, l = (r >> 3) & 63, ii = r & 7;
        int mt = ci / 9, ks = ci - mt * 9;
        int j  = mt * 32 + (l & 31);
        int kk = ks * 16 + (l >> 5) * 8 + ii;
        if (kk < 128) v = W1[kk * 128 + j];
        else if (kk == 128) v = b1[j];
        ws[i] = (_Float16)v;
    } else if (i < w2end) {
        int r = i - w1end;
        int ks = r >> 9, l = (r >> 3) & 63, ii = r & 7;
        int o  = l & 31;
        int kk = ks * 16 + (l >> 5) * 8 + ii;
        if (o < 3) {
            if (kk < 128) v = W2[kk * 3 + o];
            else if (kk == 128) v = b2[o];
        }
        ws[i] = (_Float16)v;
    }
}

union U4 { unsigned u[4]; half8 h; };

__device__ __forceinline__ unsigned pkr(float a, float b) {
    union { fp16x2 h; unsigned u; } x;
    x.h = __builtin_amdgcn_cvt_pkrtz(a, b);
    return x.u;
}

// acc tile (C-layout) -> two B-frag half8 chunks via relu+pack+lane^32 exchange.
__device__ __forceinline__ void transition(const floatx16& a, int hl,
                                           half8& lo, half8& hi) {
    unsigned p0 = pkr(fmaxf(a[0],  0.f), fmaxf(a[1],  0.f));
    unsigned p1 = pkr(fmaxf(a[2],  0.f), fmaxf(a[3],  0.f));
    unsigned p2 = pkr(fmaxf(a[4],  0.f), fmaxf(a[5],  0.f));
    unsigned p3 = pkr(fmaxf(a[6],  0.f), fmaxf(a[7],  0.f));
    unsigned p4 = pkr(fmaxf(a[8],  0.f), fmaxf(a[9],  0.f));
    unsigned p5 = pkr(fmaxf(a[10], 0.f), fmaxf(a[11], 0.f));
    unsigned p6 = pkr(fmaxf(a[12], 0.f), fmaxf(a[13], 0.f));
    unsigned p7 = pkr(fmaxf(a[14], 0.f), fmaxf(a[15], 0.f));
    unsigned r0 = __shfl_xor(hl ? p0 : p2, 32);
    unsigned r1 = __shfl_xor(hl ? p1 : p3, 32);
    unsigned r2 = __shfl_xor(hl ? p4 : p6, 32);
    unsigned r3 = __shfl_xor(hl ? p5 : p7, 32);
    U4 L, H;
    L.u[0] = hl ? r0 : p0;
    L.u[1] = hl ? r1 : p1;
    L.u[2] = hl ? p2 : r0;
    L.u[3] = hl ? p3 : r1;
    H.u[0] = hl ? r2 : p4;
    H.u[1] = hl ? r3 : p5;
    H.u[2] = hl ? p6 : r2;
    H.u[3] = hl ? p7 : r3;
    lo = L.h; hi = H.h;
}

#define MFMA(a, b, c) __builtin_amdgcn_mfma_f32_32x32x16_f16((a), (b), (c), 0, 0, 0)

// LDS frag arena: W0c chunks 0..15 @0, W1 chunks @16384, W2 chunks @53248. 62464 B.
__global__ __launch_bounds__(512, 4) void vdc_mlp_kernel(
    const float* __restrict__ feats,      // [N,32]
    const float* __restrict__ dirs,       // [C,N,3]
    const int* __restrict__ sh_deg_p,     // [1]
    const _Float16* __restrict__ ws,
    float* __restrict__ out,              // [C,N,3]
    int N, int C)
{
    __shared__ uint4 arena[3904];         // 62464 B
    char* lds = (char*)arena;

    const int tid   = threadIdx.x;
    const int c     = blockIdx.y;
    const int w     = tid >> 6;           // 0..7
    const int lane  = tid & 63;
    const int ln    = lane & 31;
    const int hl    = lane >> 5;
    const int base  = blockIdx.x * 256 + w * 32;   // this wave's 32 elements

    // ---- stage frag-linear weights into LDS (coalesced, conflict-free) ----
    {
        const uint4* srcA = (const uint4*)(ws + (size_t)c * 8192);
        const uint4* srcB = (const uint4*)(ws + (size_t)C * 8192);
        #pragma unroll
        for (int it = 0; it < 8; ++it) {
            int idx = it * 512 + tid;
            if (idx < 3904)
                arena[idx] = (idx < 1024) ? srcA[idx] : srcB[idx - 1024];
        }
    }

    // ---- build layer0 B-frags (registers only; overlaps staging) ----
    half8 bx0, bx1, bx2, bbias;
    {
        U4 ub;
        ub.u[0] = hl ? 0u : 0x00003C00u;   // f16 1.0 at k-offset 0, hl=0 only
        ub.u[1] = 0u; ub.u[2] = 0u; ub.u[3] = 0u;
        bbias = ub.h;
    }
    {
        int n = base + ln; if (n >= N) n = N - 1;
        const float* fp = feats + (size_t)n * 32 + hl * 8;
        float4 f0 = *(const float4*)(fp);
        float4 f1 = *(const float4*)(fp + 4);
        float4 f2 = *(const float4*)(fp + 16);
        float4 f3 = *(const float4*)(fp + 20);
        U4 u0, u1;
        u0.u[0] = pkr(f0.x, f0.y); u0.u[1] = pkr(f0.z, f0.w);
        u0.u[2] = pkr(f1.x, f1.y); u0.u[3] = pkr(f1.z, f1.w);
        u1.u[0] = pkr(f2.x, f2.y); u1.u[1] = pkr(f2.z, f2.w);
        u1.u[2] = pkr(f3.x, f3.y); u1.u[3] = pkr(f3.z, f3.w);
        bx0 = u0.h; bx1 = u1.h;

        const float* dp = dirs + ((size_t)c * N + n) * 3;
        float dx = dp[0], dy = dp[1], dz = dp[2];
        float nrm = sqrtf(dx * dx + dy * dy + dz * dz);
        float inv = 1.0f / fmaxf(nrm, 1e-12f);
        float x = dx * inv, y = dy * inv, z = dz * inv;

        float z2     = z * z;
        float fTmp0B = -1.092548430592079f * z;
        float fC1    = x * x - y * y;
        float fS1    = 2.0f * x * y;
        float fTmp0C = -2.285228997322329f * z2 + 0.4570457994644658f;
        float fTmp1B = 1.445305721320277f * z;
        float fC2    = x * fC1 - y * fS1;
        float fS2    = x * fS1 + y * fC1;

        float sh[16];
        sh[0]  = 0.2820947917738781f;
        sh[1]  = -0.48860251190292f * y;
        sh[2]  = 0.48860251190292f * z;
        sh[3]  = -0.48860251190292f * x;
        sh[4]  = 0.5462742152960395f * fS1;
        sh[5]  = fTmp0B * y;
        sh[6]  = 0.9461746957575601f * z2 - 0.3153915652525201f;
        sh[7]  = fTmp0B * x;
        sh[8]  = 0.5462742152960395f * fC1;
        sh[9]  = -0.5900435899266435f * fS2;
        sh[10] = fTmp1B * fS1;
        sh[11] = fTmp0C * y;
        sh[12] = z * (1.865881662950577f * z2 - 1.119528997770346f);
        sh[13] = fTmp0C * x;
        sh[14] = fTmp1B * fC1;
        sh[15] = -0.5900435899266435f * fC2;

        int deg = sh_deg_p[0];
        int nbu = (deg + 1) * (deg + 1);
        #pragma unroll
        for (int i = 0; i < 16; ++i) if (i >= nbu) sh[i] = 0.0f;

        float s[8];
        #pragma unroll
        for (int i = 0; i < 8; ++i) s[i] = hl ? sh[8 + i] : sh[i];
        U4 u2;
        u2.u[0] = pkr(s[0], s[1]); u2.u[1] = pkr(s[2], s[3]);
        u2.u[2] = pkr(s[4], s[5]); u2.u[3] = pkr(s[6], s[7]);
        bx2 = u2.h;
    }

    __syncthreads();

    const char* fr = lds + lane * 16;     // per-lane frag base; chunk offsets imm

    // ---- layer 0 + transition -> hx (only 8 live activation frags) ----
    half8 hx[8];
    #pragma unroll
    for (int mt = 0; mt < 4; ++mt) {
        half8 a0 = *(const half8*)(fr + (mt * 4 + 0) * 1024);
        half8 a1 = *(const half8*)(fr + (mt * 4 + 1) * 1024);
        half8 a2 = *(const half8*)(fr + (mt * 4 + 2) * 1024);
        half8 a3 = *(const half8*)(fr + (mt * 4 + 3) * 1024);
        floatx16 acc;
        #pragma unroll
        for (int r = 0; r < 16; ++r) acc[r] = 0.0f;
        acc = MFMA(a0, bx0, acc);
        acc = MFMA(a1, bx1, acc);
        acc = MFMA(a2, bx2, acc);
        acc = MFMA(a3, bbias, acc);
        transition(acc, hl, hx[2 * mt], hx[2 * mt + 1]);
    }

    // ---- layer 1 with layer 2 fused per mt (gx never materialized) ----
    floatx16 acc3;
    #pragma unroll
    for (int r = 0; r < 16; ++r) acc3[r] = 0.0f;

    #pragma unroll
    for (int mt = 0; mt < 4; ++mt) {
        const char* ap = fr + 16384 + mt * 9 * 1024;
        floatx16 acc;
        #pragma unroll
        for (int r = 0; r < 16; ++r) acc[r] = 0.0f;
        #pragma unroll
        for (int ks = 0; ks < 8; ++ks) {
            half8 a = *(const half8*)(ap + ks * 1024);
            acc = MFMA(a, hx[ks], acc);
        }
        half8 ab = *(const half8*)(ap + 8 * 1024);
        acc = MFMA(ab, bbias, acc);

        half8 g0, g1;
        transition(acc, hl, g0, g1);

        half8 w2a = *(const half8*)(fr + 53248 + (2 * mt + 0) * 1024);
        half8 w2b = *(const half8*)(fr + 53248 + (2 * mt + 1) * 1024);
        acc3 = MFMA(w2a, g0, acc3);
        acc3 = MFMA(w2b, g1, acc3);
    }
    {
        half8 ab = *(const half8*)(fr + 53248 + 8 * 1024);
        acc3 = MFMA(ab, bbias, acc3);
    }

    // D: col = e = ln, row = (r&3)+8*(r>>2)+4*hl -> hl=0 regs 0,1,2 are o=0,1,2
    if (hl == 0) {
        int nn = base + ln;
        if (nn < N) {
            float* op = out + ((size_t)c * N + nn) * 3;
            op[0] = acc3[0];
            op[1] = acc3[1];
            op[2] = acc3[2];
        }
    }
}

extern "C" void kernel_launch(void* const* d_in, const int* in_sizes, int n_in,
                              void* d_out, int out_size, void* d_ws, size_t ws_size,
                              hipStream_t stream) {
    const float* feats   = (const float*)d_in[0];
    const float* dirs    = (const float*)d_in[1];
    const float* emb_tab = (const float*)d_in[2];
    const float* W0      = (const float*)d_in[3];
    const float* b0      = (const float*)d_in[4];
    const float* W1      = (const float*)d_in[5];
    const float* b1      = (const float*)d_in[6];
    const float* W2      = (const float*)d_in[7];
    const float* b2      = (const float*)d_in[8];
    const int*   eids    = (const int*)d_in[9];
    const int*   shd     = (const int*)d_in[10];
    float* outp          = (float*)d_out;

    int N = in_sizes[0] / 32;    // features [N,32]
    int C = in_sizes[9];         // embed_ids [C]

    _Float16* wsh = (_Float16*)d_ws;

    int ws_elems = C * 8192 + 23040;
    vdc_prep_kernel<<<(ws_elems + 255) / 256, 256, 0, stream>>>(
        W0, W1, W2, b0, b1, b2, emb_tab, eids, C, wsh);

    dim3 grid((N + 255) / 256, C);
    vdc_mlp_kernel<<<grid, 512, 0, stream>>>(
        feats, dirs, shd, wsh, outp, N, C);
}